// Round 3
// baseline (1724.473 us; speedup 1.0000x reference)
//
#include <hip/hip_runtime.h>

typedef unsigned int u32;
typedef unsigned short ushort_t;

typedef __attribute__((ext_vector_type(8))) short bf16x8;   // 8 bf16 = 4 VGPR
typedef __attribute__((ext_vector_type(4))) float f32x4;    // MFMA acc
typedef __attribute__((ext_vector_type(4))) u32 u32x4;

#define ENS 10
#define NU 256
#define NHID 7
#define IN_DIM 6
#define OUT_DIM 201
#define BATCH 16384

// fragment-array sizes in ushort (bf16) elements
#define WH_PER 65536                 // per (layer, ens): 8 s * 16 ct * 64 lanes * 8
#define WH_TOT (NHID * ENS * WH_PER) // 4,587,520
#define W0_PER (16 * 64 * 8)         // 8192 per ens (1 k-step, K padded 6->32)
#define W0_TOT (ENS * W0_PER)
#define WF_PER (8 * 13 * 64 * 8)     // 53248 per ens (N padded 201->208)
#define WF_TOT (ENS * WF_PER)
#define X_TOT ((BATCH / 16) * 64 * 8) // 524,288 (K padded 6->32, 8 per lane)

// ws layout (ushort units); total ~23 MB
#define O_WHH 0
#define O_WHL (O_WHH + WH_TOT)
#define O_W0H (O_WHL + WH_TOT)
#define O_W0L (O_W0H + W0_TOT)
#define O_WFH (O_W0L + W0_TOT)
#define O_WFL (O_WFH + WF_TOT)
#define O_XH  (O_WFL + WF_TOT)
#define O_XL  (O_XH + X_TOT)

#define RT 64        // batch rows per WG (64 rows -> 66.6 KB LDS -> 2 WG/CU)
#define MT 2         // 16-row tiles per wave (32 rows/wave)
#define ACT_LD 260   // padded row stride (u32); 1040B: 16B-aligned, bank-shift 4/row

__device__ __forceinline__ u32 bf16_rne(float f) {
    u32 u = __float_as_uint(f);
    return (u + 0x7FFFu + ((u >> 16) & 1u)) >> 16;
}
__device__ __forceinline__ void split2(float f, u32& h, u32& l) {
    h = bf16_rne(f);
    float fh = __uint_as_float(h << 16);
    l = bf16_rne(f - fh);
}

// ---------------- prep kernels: fp32 -> hi/lo bf16 in B-frag-linear layout ----------------
// B-frag (16x16x32): lane l holds col = l&15, k = (l>>4)*8 + j (j=0..7)
// storage index: ((s*CTN + ct)*64 + l)*8 + j

__global__ __launch_bounds__(256) void prep_wh(const float* __restrict__ Wh,
                                               ushort_t* __restrict__ dH, ushort_t* __restrict__ dL) {
    int i = blockIdx.x * 256 + threadIdx.x;
    if (i >= WH_TOT) return;
    int le  = i >> 16;            // /65536
    int idx = i & 65535;
    int j = idx & 7, l = (idx >> 3) & 63, ct = (idx >> 9) & 15, s = idx >> 13;
    int k = s * 32 + ((l >> 4) << 3) + j;
    int n = ct * 16 + (l & 15);
    float v = Wh[(size_t)le * 65536 + k * 256 + n];
    u32 h, lo; split2(v, h, lo);
    dH[i] = (ushort_t)h; dL[i] = (ushort_t)lo;
}

__global__ __launch_bounds__(256) void prep_w0(const float* __restrict__ W0,
                                               ushort_t* __restrict__ dH, ushort_t* __restrict__ dL) {
    int i = blockIdx.x * 256 + threadIdx.x;
    if (i >= W0_TOT) return;
    int e = i >> 13;              // /8192
    int idx = i & 8191;
    int j = idx & 7, l = (idx >> 3) & 63, ct = (idx >> 9) & 15;
    int k = ((l >> 4) << 3) + j;  // 0..31, valid < 6
    int n = ct * 16 + (l & 15);
    float v = (k < IN_DIM) ? W0[(e * IN_DIM + k) * 256 + n] : 0.0f;
    u32 h, lo; split2(v, h, lo);
    dH[i] = (ushort_t)h; dL[i] = (ushort_t)lo;
}

__global__ __launch_bounds__(256) void prep_wf(const float* __restrict__ Wf,
                                               ushort_t* __restrict__ dH, ushort_t* __restrict__ dL) {
    int i = blockIdx.x * 256 + threadIdx.x;
    if (i >= WF_TOT) return;
    int e = i / WF_PER;
    int idx = i - e * WF_PER;
    int j = idx & 7, l = (idx >> 3) & 63, g = idx >> 9; // g = s*13+ct, 0..103
    int s = g / 13, ct = g - s * 13;
    int k = s * 32 + ((l >> 4) << 3) + j;
    int n = ct * 16 + (l & 15);
    float v = (n < OUT_DIM) ? Wf[((size_t)e * 256 + k) * OUT_DIM + n] : 0.0f;
    u32 h, lo; split2(v, h, lo);
    dH[i] = (ushort_t)h; dL[i] = (ushort_t)lo;
}

// x -> A-frag layout: lane l holds row = rt*16 + (l&15), k = (l>>4)*8 + j
__global__ __launch_bounds__(256) void prep_x(const float* __restrict__ x,
                                              ushort_t* __restrict__ dH, ushort_t* __restrict__ dL) {
    int i = blockIdx.x * 256 + threadIdx.x;
    if (i >= X_TOT) return;
    int j = i & 7, l = (i >> 3) & 63, rt = i >> 9;
    int row = rt * 16 + (l & 15);
    int k = ((l >> 4) << 3) + j;
    float v = (k < IN_DIM) ? x[row * IN_DIM + k] : 0.0f;
    u32 h, lo; split2(v, h, lo);
    dH[i] = (ushort_t)h; dL[i] = (ushort_t)lo;
}

__global__ __launch_bounds__(256) void zero_out_kernel(float* __restrict__ out, int n) {
    int i = blockIdx.x * blockDim.x + threadIdx.x;
    int stride = gridDim.x * blockDim.x;
    for (; i < n; i += stride) out[i] = 0.0f;
}

// ---------------- unpack packed (hi<<16|lo) u32 x8 -> two bf16x8 frags ----------------
__device__ __forceinline__ void unpack8(u32x4 r0, u32x4 r1, bf16x8& hi, bf16x8& lo) {
    union { u32 u[4]; bf16x8 v; } H, L;
    H.u[0] = __builtin_amdgcn_perm(r0.y, r0.x, 0x07060302u);
    H.u[1] = __builtin_amdgcn_perm(r0.w, r0.z, 0x07060302u);
    H.u[2] = __builtin_amdgcn_perm(r1.y, r1.x, 0x07060302u);
    H.u[3] = __builtin_amdgcn_perm(r1.w, r1.z, 0x07060302u);
    L.u[0] = __builtin_amdgcn_perm(r0.y, r0.x, 0x05040100u);
    L.u[1] = __builtin_amdgcn_perm(r0.w, r0.z, 0x05040100u);
    L.u[2] = __builtin_amdgcn_perm(r1.y, r1.x, 0x05040100u);
    L.u[3] = __builtin_amdgcn_perm(r1.w, r1.z, 0x05040100u);
    hi = H.v; lo = L.v;
}

// ---------------- fused MLP, split-bf16 MFMA ----------------
// grid (BATCH/64, ENS), 512 threads (8 waves: 2 row-groups x 4 col-groups),
// 66.6 KB LDS -> 2 WGs/CU co-resident -> 4 waves/SIMD.
__global__ __launch_bounds__(512, 4)
void mlp_mfma(const ushort_t* __restrict__ wsU,
              const float* __restrict__ b0g, const float* __restrict__ bhg,
              const float* __restrict__ bfg, float* __restrict__ out) {
    __shared__ u32 act[RT * ACT_LD];   // 66,560 B

    const int tid  = threadIdx.x;
    const int lane = tid & 63;
    const int wave = tid >> 6;
    const int rg   = wave >> 2;      // 0..1 row group (32 rows)
    const int cg   = wave & 3;       // 0..3 col group (64 cols)
    const int l15  = lane & 15;
    const int lq   = lane >> 4;      // quarter
    const int e    = blockIdx.y;
    const int rowWG = blockIdx.x * RT;

    f32x4 acc[MT][4];
    const f32x4 vz = 0.0f;

    // ================ layer 0 (K padded to 32, 1 k-step) ================
    {
        const ushort_t* B0H = wsU + O_W0H + e * W0_PER;
        const ushort_t* B0L = wsU + O_W0L + e * W0_PER;
        bf16x8 bh_[4], bl_[4], ah[MT], al[MT];
#pragma unroll
        for (int ct = 0; ct < 4; ++ct) {
            size_t boff = ((size_t)((cg * 4 + ct) * 64 + lane)) * 8;
            bh_[ct] = *(const bf16x8*)(B0H + boff);
            bl_[ct] = *(const bf16x8*)(B0L + boff);
        }
#pragma unroll
        for (int mt = 0; mt < MT; ++mt) {
            int rt = blockIdx.x * (RT / 16) + rg * MT + mt;
            size_t xoff = ((size_t)rt * 64 + lane) * 8;
            ah[mt] = *(const bf16x8*)(wsU + O_XH + xoff);
            al[mt] = *(const bf16x8*)(wsU + O_XL + xoff);
        }
#pragma unroll
        for (int mt = 0; mt < MT; ++mt)
#pragma unroll
            for (int ct = 0; ct < 4; ++ct) {
                f32x4 a = vz;
                a = __builtin_amdgcn_mfma_f32_16x16x32_bf16(ah[mt], bh_[ct], a, 0, 0, 0);
                a = __builtin_amdgcn_mfma_f32_16x16x32_bf16(al[mt], bh_[ct], a, 0, 0, 0);
                a = __builtin_amdgcn_mfma_f32_16x16x32_bf16(ah[mt], bl_[ct], a, 0, 0, 0);
                acc[mt][ct] = a;
            }
        // epilogue -> act
        const float* bias = b0g + e * NU;
#pragma unroll
        for (int mt = 0; mt < MT; ++mt)
#pragma unroll
            for (int ct = 0; ct < 4; ++ct) {
                int col = cg * 64 + ct * 16 + l15;
                float bv = bias[col];
                int rowb = rg * 32 + mt * 16 + lq * 4;
#pragma unroll
                for (int r = 0; r < 4; ++r) {
                    float f = fmaxf(acc[mt][ct][r] + bv, 0.0f);
                    u32 h, lo; split2(f, h, lo);
                    act[(rowb + r) * ACT_LD + col] = (h << 16) | lo;
                }
            }
        __syncthreads();
    }

    // ================ 7 hidden layers (K = 256, 8 k-steps) ================
#pragma unroll 1
    for (int L = 0; L < NHID; ++L) {
        const ushort_t* BH = wsU + O_WHH + (size_t)(L * ENS + e) * WH_PER;
        const ushort_t* BL = wsU + O_WHL + (size_t)(L * ENS + e) * WH_PER;
#pragma unroll
        for (int mt = 0; mt < MT; ++mt)
#pragma unroll
            for (int ct = 0; ct < 4; ++ct) acc[mt][ct] = vz;

#pragma unroll
        for (int s = 0; s < 8; ++s) {
            bf16x8 bh_[4], bl_[4];
#pragma unroll
            for (int ct = 0; ct < 4; ++ct) {
                size_t boff = ((size_t)((s * 16 + cg * 4 + ct) * 64 + lane)) * 8;
                bh_[ct] = *(const bf16x8*)(BH + boff);
                bl_[ct] = *(const bf16x8*)(BL + boff);
            }
            bf16x8 ah[MT], al[MT];
#pragma unroll
            for (int mt = 0; mt < MT; ++mt) {
                int row = rg * 32 + mt * 16 + l15;
                int c0  = s * 32 + lq * 8;
                const u32* ap = act + row * ACT_LD + c0;
                u32x4 r0 = *(const u32x4*)ap;
                u32x4 r1 = *(const u32x4*)(ap + 4);
                unpack8(r0, r1, ah[mt], al[mt]);
            }
#pragma unroll
            for (int mt = 0; mt < MT; ++mt)
#pragma unroll
                for (int ct = 0; ct < 4; ++ct) {
                    f32x4 a = acc[mt][ct];
                    a = __builtin_amdgcn_mfma_f32_16x16x32_bf16(ah[mt], bh_[ct], a, 0, 0, 0);
                    a = __builtin_amdgcn_mfma_f32_16x16x32_bf16(al[mt], bh_[ct], a, 0, 0, 0);
                    a = __builtin_amdgcn_mfma_f32_16x16x32_bf16(ah[mt], bl_[ct], a, 0, 0, 0);
                    acc[mt][ct] = a;
                }
        }
        __syncthreads();   // all act reads done before overwrite
        const float* bias = bhg + (size_t)(L * ENS + e) * NU;
#pragma unroll
        for (int mt = 0; mt < MT; ++mt)
#pragma unroll
            for (int ct = 0; ct < 4; ++ct) {
                int col = cg * 64 + ct * 16 + l15;
                float bv = bias[col];
                int rowb = rg * 32 + mt * 16 + lq * 4;
#pragma unroll
                for (int r = 0; r < 4; ++r) {
                    float f = fmaxf(acc[mt][ct][r] + bv, 0.0f);
                    u32 h, lo; split2(f, h, lo);
                    act[(rowb + r) * ACT_LD + col] = (h << 16) | lo;
                }
            }
        __syncthreads();
    }

    // ================ final layer (N padded 201->208 = 13 ct) ================
    {
        const ushort_t* BfH = wsU + O_WFH + e * WF_PER;
        const ushort_t* BfL = wsU + O_WFL + e * WF_PER;
        const int nt = (cg == 0) ? 4 : 3;   // ct_global = cg + 4*jj, valid < 13
#pragma unroll
        for (int mt = 0; mt < MT; ++mt)
#pragma unroll
            for (int jj = 0; jj < 4; ++jj) acc[mt][jj] = vz;

#pragma unroll
        for (int s = 0; s < 8; ++s) {
            bf16x8 ah[MT], al[MT];
#pragma unroll
            for (int mt = 0; mt < MT; ++mt) {
                int row = rg * 32 + mt * 16 + l15;
                int c0  = s * 32 + lq * 8;
                const u32* ap = act + row * ACT_LD + c0;
                u32x4 r0 = *(const u32x4*)ap;
                u32x4 r1 = *(const u32x4*)(ap + 4);
                unpack8(r0, r1, ah[mt], al[mt]);
            }
#pragma unroll
            for (int jj = 0; jj < 4; ++jj) {
                if (jj < nt) {
                    int ctg = cg + 4 * jj;
                    size_t boff = ((size_t)((s * 13 + ctg) * 64 + lane)) * 8;
                    bf16x8 bh_ = *(const bf16x8*)(BfH + boff);
                    bf16x8 bl_ = *(const bf16x8*)(BfL + boff);
#pragma unroll
                    for (int mt = 0; mt < MT; ++mt) {
                        f32x4 a = acc[mt][jj];
                        a = __builtin_amdgcn_mfma_f32_16x16x32_bf16(ah[mt], bh_, a, 0, 0, 0);
                        a = __builtin_amdgcn_mfma_f32_16x16x32_bf16(al[mt], bh_, a, 0, 0, 0);
                        a = __builtin_amdgcn_mfma_f32_16x16x32_bf16(ah[mt], bl_, a, 0, 0, 0);
                        acc[mt][jj] = a;
                    }
                }
            }
        }
        // strided-mean epilogue: out[b][(e*201+o)/10] += 0.1 * (y + bias)
        const float* bias = bfg + e * OUT_DIM;
#pragma unroll
        for (int jj = 0; jj < 4; ++jj) {
            int ctg = cg + 4 * jj;
            if (jj < nt) {
                int o = ctg * 16 + l15;
                if (o < OUT_DIM) {
                    float bv = bias[o];
                    int flatc = e * OUT_DIM + o;
                    int jo = flatc / 10;
#pragma unroll
                    for (int mt = 0; mt < MT; ++mt) {
#pragma unroll
                        for (int r = 0; r < 4; ++r) {
                            int rowg = rowWG + rg * 32 + mt * 16 + lq * 4 + r;
                            atomicAdd(out + (size_t)rowg * OUT_DIM + jo,
                                      0.1f * (acc[mt][jj][r] + bv));
                        }
                    }
                }
            }
        }
    }
}

extern "C" void kernel_launch(void* const* d_in, const int* in_sizes, int n_in,
                              void* d_out, int out_size, void* d_ws, size_t ws_size,
                              hipStream_t stream) {
    const float* x  = (const float*)d_in[0];
    const float* W0 = (const float*)d_in[1];
    const float* b0 = (const float*)d_in[2];
    const float* Wh = (const float*)d_in[3];
    const float* bh = (const float*)d_in[4];
    const float* Wf = (const float*)d_in[5];
    const float* bf = (const float*)d_in[6];
    float* out = (float*)d_out;
    ushort_t* ws = (ushort_t*)d_ws;   // needs ~23 MB

    prep_wh<<<(WH_TOT + 255) / 256, 256, 0, stream>>>(Wh, ws + O_WHH, ws + O_WHL);
    prep_w0<<<(W0_TOT + 255) / 256, 256, 0, stream>>>(W0, ws + O_W0H, ws + O_W0L);
    prep_wf<<<(WF_TOT + 255) / 256, 256, 0, stream>>>(Wf, ws + O_WFH, ws + O_WFL);
    prep_x <<<(X_TOT  + 255) / 256, 256, 0, stream>>>(x,  ws + O_XH,  ws + O_XL);
    zero_out_kernel<<<2048, 256, 0, stream>>>(out, out_size);

    dim3 grid(BATCH / RT, ENS);
    mlp_mfma<<<grid, 512, 0, stream>>>(ws, b0, bh, bf, out);
}

// Round 4
// 1624.143 us; speedup vs baseline: 1.0618x; 1.0618x over previous
//
#include <hip/hip_runtime.h>

typedef unsigned int u32;
typedef unsigned short ushort_t;

typedef __attribute__((ext_vector_type(8))) short bf16x8;   // 8 bf16 = 4 VGPR
typedef __attribute__((ext_vector_type(4))) float f32x4;    // MFMA acc
typedef __attribute__((ext_vector_type(4))) u32 u32x4;

#define ENS 10
#define NU 256
#define NHID 7
#define IN_DIM 6
#define OUT_DIM 201
#define BATCH 16384

// fragment-array sizes in ushort (bf16) elements
#define WH_PER 65536                 // per (layer, ens): 8 s * 16 ct * 64 lanes * 8
#define WH_TOT (NHID * ENS * WH_PER) // 4,587,520
#define W0_PER (16 * 64 * 8)         // 8192 per ens (1 k-step, K padded 6->32)
#define W0_TOT (ENS * W0_PER)
#define WF_PER (8 * 13 * 64 * 8)     // 53248 per ens (N padded 201->208)
#define WF_TOT (ENS * WF_PER)
#define X_TOT ((BATCH / 16) * 64 * 8) // 524,288 (K padded 6->32, 8 per lane)

// ws layout (ushort units); total ~23 MB
#define O_WHH 0
#define O_WHL (O_WHH + WH_TOT)
#define O_W0H (O_WHL + WH_TOT)
#define O_W0L (O_W0H + W0_TOT)
#define O_WFH (O_W0L + W0_TOT)
#define O_WFL (O_WFH + WF_TOT)
#define O_XH  (O_WFL + WF_TOT)
#define O_XL  (O_XH + X_TOT)

#define RT 64        // batch rows per WG (64 rows -> 66.6 KB LDS -> 2 WG/CU)
#define ACT_LD 260   // padded row stride (u32); 1040B: 16B-aligned

__device__ __forceinline__ u32 bf16_rne(float f) {
    u32 u = __float_as_uint(f);
    return (u + 0x7FFFu + ((u >> 16) & 1u)) >> 16;
}
__device__ __forceinline__ void split2(float f, u32& h, u32& l) {
    h = bf16_rne(f);
    float fh = __uint_as_float(h << 16);
    l = bf16_rne(f - fh);
}

// ---------------- prep kernels: fp32 -> hi/lo bf16 in B-frag-linear layout ----------------
// B-frag (16x16x32): lane l holds col = l&15, k = (l>>4)*8 + j (j=0..7)
// storage index: ((s*CTN + ct)*64 + l)*8 + j

__global__ __launch_bounds__(256) void prep_wh(const float* __restrict__ Wh,
                                               ushort_t* __restrict__ dH, ushort_t* __restrict__ dL) {
    int i = blockIdx.x * 256 + threadIdx.x;
    if (i >= WH_TOT) return;
    int le  = i >> 16;            // /65536
    int idx = i & 65535;
    int j = idx & 7, l = (idx >> 3) & 63, ct = (idx >> 9) & 15, s = idx >> 13;
    int k = s * 32 + ((l >> 4) << 3) + j;
    int n = ct * 16 + (l & 15);
    float v = Wh[(size_t)le * 65536 + k * 256 + n];
    u32 h, lo; split2(v, h, lo);
    dH[i] = (ushort_t)h; dL[i] = (ushort_t)lo;
}

__global__ __launch_bounds__(256) void prep_w0(const float* __restrict__ W0,
                                               ushort_t* __restrict__ dH, ushort_t* __restrict__ dL) {
    int i = blockIdx.x * 256 + threadIdx.x;
    if (i >= W0_TOT) return;
    int e = i >> 13;              // /8192
    int idx = i & 8191;
    int j = idx & 7, l = (idx >> 3) & 63, ct = (idx >> 9) & 15;
    int k = ((l >> 4) << 3) + j;  // 0..31, valid < 6
    int n = ct * 16 + (l & 15);
    float v = (k < IN_DIM) ? W0[(e * IN_DIM + k) * 256 + n] : 0.0f;
    u32 h, lo; split2(v, h, lo);
    dH[i] = (ushort_t)h; dL[i] = (ushort_t)lo;
}

__global__ __launch_bounds__(256) void prep_wf(const float* __restrict__ Wf,
                                               ushort_t* __restrict__ dH, ushort_t* __restrict__ dL) {
    int i = blockIdx.x * 256 + threadIdx.x;
    if (i >= WF_TOT) return;
    int e = i / WF_PER;
    int idx = i - e * WF_PER;
    int j = idx & 7, l = (idx >> 3) & 63, g = idx >> 9; // g = s*13+ct, 0..103
    int s = g / 13, ct = g - s * 13;
    int k = s * 32 + ((l >> 4) << 3) + j;
    int n = ct * 16 + (l & 15);
    float v = (n < OUT_DIM) ? Wf[((size_t)e * 256 + k) * OUT_DIM + n] : 0.0f;
    u32 h, lo; split2(v, h, lo);
    dH[i] = (ushort_t)h; dL[i] = (ushort_t)lo;
}

// x -> A-frag layout: lane l holds row = rt*16 + (l&15), k = (l>>4)*8 + j
__global__ __launch_bounds__(256) void prep_x(const float* __restrict__ x,
                                              ushort_t* __restrict__ dH, ushort_t* __restrict__ dL) {
    int i = blockIdx.x * 256 + threadIdx.x;
    if (i >= X_TOT) return;
    int j = i & 7, l = (i >> 3) & 63, rt = i >> 9;
    int row = rt * 16 + (l & 15);
    int k = ((l >> 4) << 3) + j;
    float v = (k < IN_DIM) ? x[row * IN_DIM + k] : 0.0f;
    u32 h, lo; split2(v, h, lo);
    dH[i] = (ushort_t)h; dL[i] = (ushort_t)lo;
}

__global__ __launch_bounds__(256) void zero_out_kernel(float* __restrict__ out, int n) {
    int i = blockIdx.x * blockDim.x + threadIdx.x;
    int stride = gridDim.x * blockDim.x;
    for (; i < n; i += stride) out[i] = 0.0f;
}

// ---------------- unpack packed (hi<<16|lo) u32 x8 -> two bf16x8 frags ----------------
__device__ __forceinline__ void unpack8(u32x4 r0, u32x4 r1, bf16x8& hi, bf16x8& lo) {
    union { u32 u[4]; bf16x8 v; } H, L;
    H.u[0] = __builtin_amdgcn_perm(r0.y, r0.x, 0x07060302u);
    H.u[1] = __builtin_amdgcn_perm(r0.w, r0.z, 0x07060302u);
    H.u[2] = __builtin_amdgcn_perm(r1.y, r1.x, 0x07060302u);
    H.u[3] = __builtin_amdgcn_perm(r1.w, r1.z, 0x07060302u);
    L.u[0] = __builtin_amdgcn_perm(r0.y, r0.x, 0x05040100u);
    L.u[1] = __builtin_amdgcn_perm(r0.w, r0.z, 0x05040100u);
    L.u[2] = __builtin_amdgcn_perm(r1.y, r1.x, 0x05040100u);
    L.u[3] = __builtin_amdgcn_perm(r1.w, r1.z, 0x05040100u);
    hi = H.v; lo = L.v;
}

// ---------------- fused MLP, split-bf16 MFMA, pipelined B ----------------
// 1-D grid 2560 with XCD swizzle; 512 threads = 8 waves, wave w owns cols
// [w*32, w*32+32) for all 64 rows (mt=4, ct=2). 66.6 KB LDS -> 2 WG/CU.
__global__ __launch_bounds__(512, 4)
void mlp_mfma(const ushort_t* __restrict__ wsU,
              const float* __restrict__ b0g, const float* __restrict__ bhg,
              const float* __restrict__ bfg, float* __restrict__ out) {
    __shared__ u32 act[RT * ACT_LD];   // 66,560 B

    const int tid  = threadIdx.x;
    const int lane = tid & 63;
    const int cg   = tid >> 6;       // wave = col group, 0..7 (32 cols each)
    const int l15  = lane & 15;
    const int lq   = lane >> 4;      // quarter

    // XCD-aware bijective swizzle: 2560 WGs, 8 XCDs, 320/XCD, e-major chunks
    const int bid  = blockIdx.x;
    const int work = (bid & 7) * 320 + (bid >> 3);
    const int e    = work >> 8;      // ensemble 0..9
    const int rb   = work & 255;     // row block 0..255
    const int rowWG = rb * RT;

    f32x4 acc[4][2];
    const f32x4 vz = 0.0f;
    bf16x8 bhc[2], blc[2];           // pipelined B (current)

    // ================ layer 0 (K padded to 32, 1 k-step) ================
    {
        const ushort_t* B0H = wsU + O_W0H + e * W0_PER;
        const ushort_t* B0L = wsU + O_W0L + e * W0_PER;
        bf16x8 b0h[2], b0l[2], ah[4], al[4];
#pragma unroll
        for (int ct = 0; ct < 2; ++ct) {
            size_t boff = ((size_t)((cg * 2 + ct) * 64 + lane)) * 8;
            b0h[ct] = *(const bf16x8*)(B0H + boff);
            b0l[ct] = *(const bf16x8*)(B0L + boff);
        }
#pragma unroll
        for (int mt = 0; mt < 4; ++mt) {
            int rt = rb * 4 + mt;
            size_t xoff = ((size_t)rt * 64 + lane) * 8;
            ah[mt] = *(const bf16x8*)(wsU + O_XH + xoff);
            al[mt] = *(const bf16x8*)(wsU + O_XL + xoff);
        }
        // prefetch hidden layer 0, s=0 B into the pipeline regs
        {
            const ushort_t* BH0 = wsU + O_WHH + (size_t)e * WH_PER;
            const ushort_t* BL0 = wsU + O_WHL + (size_t)e * WH_PER;
#pragma unroll
            for (int ct = 0; ct < 2; ++ct) {
                size_t boff = ((size_t)((cg * 2 + ct) * 64 + lane)) * 8;
                bhc[ct] = *(const bf16x8*)(BH0 + boff);
                blc[ct] = *(const bf16x8*)(BL0 + boff);
            }
        }
#pragma unroll
        for (int mt = 0; mt < 4; ++mt)
#pragma unroll
            for (int ct = 0; ct < 2; ++ct) {
                f32x4 a = vz;
                a = __builtin_amdgcn_mfma_f32_16x16x32_bf16(ah[mt], b0h[ct], a, 0, 0, 0);
                a = __builtin_amdgcn_mfma_f32_16x16x32_bf16(al[mt], b0h[ct], a, 0, 0, 0);
                a = __builtin_amdgcn_mfma_f32_16x16x32_bf16(ah[mt], b0l[ct], a, 0, 0, 0);
                acc[mt][ct] = a;
            }
        const float* bias = b0g + e * NU;
        float bv[2];
#pragma unroll
        for (int ct = 0; ct < 2; ++ct) bv[ct] = bias[cg * 32 + ct * 16 + l15];
#pragma unroll
        for (int mt = 0; mt < 4; ++mt)
#pragma unroll
            for (int ct = 0; ct < 2; ++ct) {
                int col = cg * 32 + ct * 16 + l15;
                int rowb = mt * 16 + lq * 4;
#pragma unroll
                for (int r = 0; r < 4; ++r) {
                    float f = fmaxf(acc[mt][ct][r] + bv[ct], 0.0f);
                    u32 h, lo; split2(f, h, lo);
                    act[(rowb + r) * ACT_LD + col] = (h << 16) | lo;
                }
            }
        __syncthreads();
    }

    // ================ 7 hidden layers (K = 256, 8 k-steps, B pipelined) ================
    const ushort_t* BH = wsU + O_WHH + (size_t)e * WH_PER;
    const ushort_t* BL = wsU + O_WHL + (size_t)e * WH_PER;
#pragma unroll 1
    for (int L = 0; L < NHID; ++L) {
        const float* bias = bhg + (size_t)(L * ENS + e) * NU;
        float bv[2];
#pragma unroll
        for (int ct = 0; ct < 2; ++ct) bv[ct] = bias[cg * 32 + ct * 16 + l15];
#pragma unroll
        for (int mt = 0; mt < 4; ++mt)
#pragma unroll
            for (int ct = 0; ct < 2; ++ct) acc[mt][ct] = vz;

#pragma unroll
        for (int s = 0; s < 8; ++s) {
            // prefetch s+1 B (same layer)
            bf16x8 bhn[2], bln[2];
            if (s < 7) {
#pragma unroll
                for (int ct = 0; ct < 2; ++ct) {
                    size_t boff = ((size_t)(((s + 1) * 16 + cg * 2 + ct) * 64 + lane)) * 8;
                    bhn[ct] = *(const bf16x8*)(BH + boff);
                    bln[ct] = *(const bf16x8*)(BL + boff);
                }
            }
            // A from LDS
            bf16x8 ah[4], al[4];
#pragma unroll
            for (int mt = 0; mt < 4; ++mt) {
                int row = mt * 16 + l15;
                int c0  = s * 32 + lq * 8;
                const u32* ap = act + row * ACT_LD + c0;
                u32x4 r0 = *(const u32x4*)ap;
                u32x4 r1 = *(const u32x4*)(ap + 4);
                unpack8(r0, r1, ah[mt], al[mt]);
            }
#pragma unroll
            for (int mt = 0; mt < 4; ++mt)
#pragma unroll
                for (int ct = 0; ct < 2; ++ct) {
                    f32x4 a = acc[mt][ct];
                    a = __builtin_amdgcn_mfma_f32_16x16x32_bf16(ah[mt], bhc[ct], a, 0, 0, 0);
                    a = __builtin_amdgcn_mfma_f32_16x16x32_bf16(al[mt], bhc[ct], a, 0, 0, 0);
                    a = __builtin_amdgcn_mfma_f32_16x16x32_bf16(ah[mt], blc[ct], a, 0, 0, 0);
                    acc[mt][ct] = a;
                }
            if (s < 7) {
#pragma unroll
                for (int ct = 0; ct < 2; ++ct) { bhc[ct] = bhn[ct]; blc[ct] = bln[ct]; }
            }
        }

        // prefetch next layer's s=0 B (or final layer's s=0) before the barriers,
        // so the load latency hides under epilogue + barrier.
        if (L < NHID - 1) {
            const ushort_t* nBH = BH + (size_t)ENS * WH_PER;
            const ushort_t* nBL = BL + (size_t)ENS * WH_PER;
#pragma unroll
            for (int ct = 0; ct < 2; ++ct) {
                size_t boff = ((size_t)((cg * 2 + ct) * 64 + lane)) * 8;
                bhc[ct] = *(const bf16x8*)(nBH + boff);
                blc[ct] = *(const bf16x8*)(nBL + boff);
            }
        } else {
            const ushort_t* BfH = wsU + O_WFH + (size_t)e * WF_PER;
            const ushort_t* BfL = wsU + O_WFL + (size_t)e * WF_PER;
#pragma unroll
            for (int jj = 0; jj < 2; ++jj) {
                int ctg = cg + 8 * jj;
                if (ctg < 13) {
                    size_t boff = ((size_t)(ctg * 64 + lane)) * 8;   // s=0
                    bhc[jj] = *(const bf16x8*)(BfH + boff);
                    blc[jj] = *(const bf16x8*)(BfL + boff);
                }
            }
        }

        __syncthreads();   // all act reads of this layer done before overwrite
#pragma unroll
        for (int mt = 0; mt < 4; ++mt)
#pragma unroll
            for (int ct = 0; ct < 2; ++ct) {
                int col = cg * 32 + ct * 16 + l15;
                int rowb = mt * 16 + lq * 4;
#pragma unroll
                for (int r = 0; r < 4; ++r) {
                    float f = fmaxf(acc[mt][ct][r] + bv[ct], 0.0f);
                    u32 h, lo; split2(f, h, lo);
                    act[(rowb + r) * ACT_LD + col] = (h << 16) | lo;
                }
            }
        __syncthreads();
        BH += (size_t)ENS * WH_PER;
        BL += (size_t)ENS * WH_PER;
    }

    // ================ final layer (N padded 201->208 = 13 ct-tiles) ================
    {
        const ushort_t* BfH = wsU + O_WFH + (size_t)e * WF_PER;
        const ushort_t* BfL = wsU + O_WFL + (size_t)e * WF_PER;
        const float* bias = bfg + e * OUT_DIM;
        float bfv[2];
        int ov[2];
#pragma unroll
        for (int jj = 0; jj < 2; ++jj) {
            int ctg = cg + 8 * jj;
            int o = ctg * 16 + l15;
            ov[jj] = (ctg < 13 && o < OUT_DIM) ? o : -1;
            bfv[jj] = (ov[jj] >= 0) ? bias[o] : 0.0f;
        }
        f32x4 facc[4][2];
#pragma unroll
        for (int mt = 0; mt < 4; ++mt)
#pragma unroll
            for (int jj = 0; jj < 2; ++jj) facc[mt][jj] = vz;

#pragma unroll
        for (int s = 0; s < 8; ++s) {
            bf16x8 bhn[2], bln[2];
            if (s < 7) {
#pragma unroll
                for (int jj = 0; jj < 2; ++jj) {
                    int ctg = cg + 8 * jj;
                    if (ctg < 13) {
                        size_t boff = ((size_t)(((s + 1) * 13 + ctg) * 64 + lane)) * 8;
                        bhn[jj] = *(const bf16x8*)(BfH + boff);
                        bln[jj] = *(const bf16x8*)(BfL + boff);
                    }
                }
            }
            bf16x8 ah[4], al[4];
#pragma unroll
            for (int mt = 0; mt < 4; ++mt) {
                int row = mt * 16 + l15;
                int c0  = s * 32 + lq * 8;
                const u32* ap = act + row * ACT_LD + c0;
                u32x4 r0 = *(const u32x4*)ap;
                u32x4 r1 = *(const u32x4*)(ap + 4);
                unpack8(r0, r1, ah[mt], al[mt]);
            }
#pragma unroll
            for (int jj = 0; jj < 2; ++jj) {
                if (cg + 8 * jj < 13) {
#pragma unroll
                    for (int mt = 0; mt < 4; ++mt) {
                        f32x4 a = facc[mt][jj];
                        a = __builtin_amdgcn_mfma_f32_16x16x32_bf16(ah[mt], bhc[jj], a, 0, 0, 0);
                        a = __builtin_amdgcn_mfma_f32_16x16x32_bf16(al[mt], bhc[jj], a, 0, 0, 0);
                        a = __builtin_amdgcn_mfma_f32_16x16x32_bf16(ah[mt], blc[jj], a, 0, 0, 0);
                        facc[mt][jj] = a;
                    }
                }
            }
            if (s < 7) {
#pragma unroll
                for (int jj = 0; jj < 2; ++jj) { bhc[jj] = bhn[jj]; blc[jj] = bln[jj]; }
            }
        }
        // strided-mean epilogue: out[b][(e*201+o)/10] += 0.1 * (y + bias)
#pragma unroll
        for (int jj = 0; jj < 2; ++jj) {
            if (ov[jj] >= 0) {
                int flatc = e * OUT_DIM + ov[jj];
                int jo = flatc / 10;
#pragma unroll
                for (int mt = 0; mt < 4; ++mt) {
#pragma unroll
                    for (int r = 0; r < 4; ++r) {
                        int rowg = rowWG + mt * 16 + lq * 4 + r;
                        atomicAdd(out + (size_t)rowg * OUT_DIM + jo,
                                  0.1f * (facc[mt][jj][r] + bfv[jj]));
                    }
                }
            }
        }
    }
}

extern "C" void kernel_launch(void* const* d_in, const int* in_sizes, int n_in,
                              void* d_out, int out_size, void* d_ws, size_t ws_size,
                              hipStream_t stream) {
    const float* x  = (const float*)d_in[0];
    const float* W0 = (const float*)d_in[1];
    const float* b0 = (const float*)d_in[2];
    const float* Wh = (const float*)d_in[3];
    const float* bh = (const float*)d_in[4];
    const float* Wf = (const float*)d_in[5];
    const float* bf = (const float*)d_in[6];
    float* out = (float*)d_out;
    ushort_t* ws = (ushort_t*)d_ws;   // needs ~23 MB

    prep_wh<<<(WH_TOT + 255) / 256, 256, 0, stream>>>(Wh, ws + O_WHH, ws + O_WHL);
    prep_w0<<<(W0_TOT + 255) / 256, 256, 0, stream>>>(W0, ws + O_W0H, ws + O_W0L);
    prep_wf<<<(WF_TOT + 255) / 256, 256, 0, stream>>>(Wf, ws + O_WFH, ws + O_WFL);
    prep_x <<<(X_TOT  + 255) / 256, 256, 0, stream>>>(x,  ws + O_XH,  ws + O_XL);
    zero_out_kernel<<<2048, 256, 0, stream>>>(out, out_size);

    mlp_mfma<<<dim3(BATCH / RT * ENS), 512, 0, stream>>>(ws, b0, bh, bf, out);
}